// Round 8
// baseline (251.018 us; speedup 1.0000x reference)
//
#include <hip/hip_runtime.h>
#include <cstddef>
#include <cstdint>

typedef float f32x4 __attribute__((ext_vector_type(4)));
typedef __bf16 bf16x8 __attribute__((ext_vector_type(8)));

constexpr int NB = 16;   // batch
constexpr int NP = 512;  // pieces
constexpr int ND = 1024; // dim
constexpr int NW = 400;  // words
constexpr int NT = 32;   // triggers
constexpr int NE = 64;   // entities
constexpr int NH = 600;  // hidden
// W0pre: [nc=5][kb=32] images (128n x 64k bf16, XOR swizzle) - slices a,b.
// W0pair: [nc=2][it=64] images (320n x 32c bf16, rotation swizzle):
//   chunk c<2 -> W0c k = it*16 + c*8 + j ; c>=2 -> W0d k = it*16 + (c-2)*8 + j
//   elem at row r, slot ((r>>1) + c) & 3  (addr r*32 + slot*8), 0-pad n>=600.
constexpr int IMGP = 128 * 64;   // W0pre image elems
constexpr int IMGQ = 320 * 32;   // W0pair image elems

__device__ inline bf16x8 pack8(float a0, float a1, float a2, float a3,
                               float a4, float a5, float a6, float a7) {
    bf16x8 v;
    v[0] = (__bf16)a0; v[1] = (__bf16)a1; v[2] = (__bf16)a2; v[3] = (__bf16)a3;
    v[4] = (__bf16)a4; v[5] = (__bf16)a5; v[6] = (__bf16)a6; v[7] = (__bf16)a7;
    return v;
}

__device__ inline void dma16(const void* g, void* l) {
    __builtin_amdgcn_global_load_lds(
        (const __attribute__((address_space(1))) uint32_t*)g,
        (__attribute__((address_space(3))) uint32_t*)l, 16, 0, 0);
}

// ---------------------------------------------------------------------------
// Kernel 1: word means over piece intervals. grid = NB*NW, block = 256.
__global__ __launch_bounds__(256) void word_mean_kernel(
    const float* __restrict__ piece, const int* __restrict__ widx,
    float* __restrict__ word) {
    int bw = blockIdx.x;
    int b = bw / NW;
    int s = widx[bw * 2], e = widx[bw * 2 + 1];
    int col = threadIdx.x * 4;
    const float* base = piece + (size_t)b * NP * ND + col;
    float4 acc = make_float4(0.f, 0.f, 0.f, 0.f);
    for (int r = s; r < e; ++r) {
        float4 v = *(const float4*)(base + (size_t)r * ND);
        acc.x += v.x; acc.y += v.y; acc.z += v.z; acc.w += v.w;
    }
    float inv = 1.0f / (float)(e - s);
    acc.x *= inv; acc.y *= inv; acc.z *= inv; acc.w *= inv;
    *(float4*)(word + (size_t)bw * ND + col) = acc;
}

// ---------------------------------------------------------------------------
// Kernel 2: span means over word intervals (trig + ent in one grid).
__global__ __launch_bounds__(256) void span_mean_kernel(
    const float* __restrict__ word, const int* __restrict__ tidx,
    const int* __restrict__ eidx, float* __restrict__ trig,
    float* __restrict__ ent) {
    int id = blockIdx.x;
    const int* idx;
    float* out;
    int b;
    if (id < NB * NT) {
        b = id / NT; idx = tidx + id * 2; out = trig + (size_t)id * ND;
    } else {
        int id2 = id - NB * NT;
        b = id2 / NE; idx = eidx + id2 * 2; out = ent + (size_t)id2 * ND;
    }
    int s = idx[0], e = idx[1];
    int col = threadIdx.x * 4;
    const float* base = word + (size_t)b * NW * ND + col;
    float4 acc = make_float4(0.f, 0.f, 0.f, 0.f);
    for (int r = s; r < e; ++r) {
        float4 v = *(const float4*)(base + (size_t)r * ND);
        acc.x += v.x; acc.y += v.y; acc.z += v.z; acc.w += v.w;
    }
    float inv = 1.0f / (float)(e - s);
    acc.x *= inv; acc.y *= inv; acc.z *= inv; acc.w *= inv;
    *(float4*)(out + col) = acc;
}

// ---------------------------------------------------------------------------
// Kernel 3a: W0 slices a,b -> W0pre images (XOR swizzle).
// grid = (kb=32, nc=5), block = 256.
__global__ __launch_bounds__(256) void w0_swizzle_kernel(
    const float* __restrict__ W0, __bf16* __restrict__ W0pre) {
    __shared__ float T[64][132];
    int kb = blockIdx.x, nc = blockIdx.y;
    int t = threadIdx.x;
    {
        int kl = t >> 2;
        int n0 = (t & 3) * 32;
        int kg = kb * 64 + kl;
        const float* src = W0 + (size_t)kg * NH + nc * 128 + n0;
#pragma unroll
        for (int g = 0; g < 8; ++g) {
            int n = nc * 128 + n0 + g * 4;
            float4 v = (n < NH) ? *(const float4*)(src + g * 4)
                                : make_float4(0.f, 0.f, 0.f, 0.f);
            *(float4*)&T[kl][n0 + g * 4] = v;
        }
    }
    __syncthreads();
#pragma unroll
    for (int s = 0; s < 4; ++s) {
        int idx = t * 4 + s;
        int row = idx >> 3, c = idx & 7;
        bf16x8 v = pack8(T[c * 8 + 0][row], T[c * 8 + 1][row],
                         T[c * 8 + 2][row], T[c * 8 + 3][row],
                         T[c * 8 + 4][row], T[c * 8 + 5][row],
                         T[c * 8 + 6][row], T[c * 8 + 7][row]);
        __bf16* img = W0pre + ((size_t)nc * 32 + kb) * IMGP;
        *(bf16x8*)&img[row * 64 + ((c ^ (row & 7)) << 3)] = v;
    }
}

// ---------------------------------------------------------------------------
// Kernel 3b: W0 slices c,d -> W0pair images (rotation swizzle, kreal=16).
// grid = (it=64, nc=2, zz=4 of 80 rows), block = 256.
__global__ __launch_bounds__(256) void w0_pair_kernel(
    const float* __restrict__ W0, __bf16* __restrict__ W0pair) {
    __shared__ float T[32][84];   // [kidx 0..31][n-local 0..79]
    int it = blockIdx.x, nc = blockIdx.y, zz = blockIdx.z;
    int tid = threadIdx.x;
    {
        int kidx = tid >> 3, part = tid & 7;   // 10 n per thread
        int korig = (kidx < 16) ? (2048 + it * 16 + kidx)
                                : (3072 + it * 16 + (kidx - 16));
        const float* src = W0 + (size_t)korig * NH;
#pragma unroll
        for (int g = 0; g < 10; ++g) {
            int n = nc * 320 + zz * 80 + part * 10 + g;
            T[kidx][part * 10 + g] = (n < NH) ? src[n] : 0.0f;
        }
    }
    __syncthreads();
    __bf16* img = W0pair + ((size_t)nc * 64 + it) * IMGQ;
#pragma unroll
    for (int s = 0; s < 2; ++s) {
        int idx = s * 256 + tid;   // (rloc, c)
        if (idx < 320) {
            int rloc = idx >> 2, c = idx & 3;
            bf16x8 v = pack8(T[c * 8 + 0][rloc], T[c * 8 + 1][rloc],
                             T[c * 8 + 2][rloc], T[c * 8 + 3][rloc],
                             T[c * 8 + 4][rloc], T[c * 8 + 5][rloc],
                             T[c * 8 + 6][rloc], T[c * 8 + 7][rloc]);
            int rg = zz * 80 + rloc;
            int slot = ((rg >> 1) + c) & 3;
            *(bf16x8*)&img[rg * 32 + slot * 8] = v;
        }
    }
}

// ---------------------------------------------------------------------------
// Kernel 4: pre-projection GEMMs. 128x128 tiles, block = 256 (4 waves 2x2).
// grid = (12 mtile [0..3 trig, 4..11 ent], 5 nc).
__global__ __launch_bounds__(256) void pre_mfma_kernel(
    const float* __restrict__ trig, const float* __restrict__ ent,
    const __bf16* __restrict__ W0pre, float* __restrict__ pre_t,
    float* __restrict__ pre_e) {
    __shared__ __bf16 As[128 * 64];
    __shared__ __bf16 Bs[128 * 64];
    int mb = blockIdx.x, nc = blockIdx.y;
    const float* A;
    float* C;
    int kbofs, mbase;
    if (mb < 4) { A = trig; C = pre_t; kbofs = 0;  mbase = mb * 128; }
    else        { A = ent;  C = pre_e; kbofs = 16; mbase = (mb - 4) * 128; }
    int tid = threadIdx.x;
    int lane = tid & 63, w = tid >> 6, rw = w & 1, cw = w >> 1;
    int q = lane >> 4, l15 = lane & 15, sa = l15 & 7;
    int ar = tid >> 1, ah = tid & 1;
    const __bf16* imgbase = W0pre + ((size_t)nc * 32 + kbofs) * IMGP;
    f32x4 acc[4][4] = {};

    for (int it = 0; it < 16; ++it) {
        __syncthreads();
        // B: 16 KB image via DMA; each wave stages 2048 elems (4 x 512).
        const __bf16* img = imgbase + (size_t)it * IMGP + w * 2048;
#pragma unroll
        for (int i = 0; i < 4; ++i)
            dma16(img + i * 512 + lane * 8, (__bf16*)Bs + w * 2048 + i * 512);
        // A: f32 -> bf16 swizzled; thread = (row, k-half)
        {
            const float* src = A + (size_t)(mbase + ar) * ND + it * 64 + ah * 32;
#pragma unroll
            for (int i = 0; i < 4; ++i) {
                float4 a0 = *(const float4*)(src + i * 8);
                float4 a1 = *(const float4*)(src + i * 8 + 4);
                int c = ah * 4 + i;
                *(bf16x8*)&As[ar * 64 + ((c ^ (ar & 7)) << 3)] =
                    pack8(a0.x, a0.y, a0.z, a0.w, a1.x, a1.y, a1.z, a1.w);
            }
        }
        __syncthreads();
#pragma unroll
        for (int ks = 0; ks < 2; ++ks) {
            int coff = ((q ^ sa) ^ (ks << 2)) << 3;
            bf16x8 af[4];
#pragma unroll
            for (int mt = 0; mt < 4; ++mt)
                af[mt] = *(const bf16x8*)&As[(64 * rw + 16 * mt + l15) * 64 + coff];
#pragma unroll
            for (int nt = 0; nt < 4; ++nt) {
                bf16x8 bf = *(const bf16x8*)&Bs[(64 * cw + 16 * nt + l15) * 64 + coff];
#pragma unroll
                for (int mt = 0; mt < 4; ++mt)
                    acc[mt][nt] = __builtin_amdgcn_mfma_f32_16x16x32_bf16(
                        af[mt], bf, acc[mt][nt], 0, 0, 0);
            }
        }
    }
#pragma unroll
    for (int mt = 0; mt < 4; ++mt)
#pragma unroll
        for (int r = 0; r < 4; ++r) {
            float* crow =
                C + (size_t)(mbase + 64 * rw + 16 * mt + 4 * q + r) * NH;
#pragma unroll
            for (int nt = 0; nt < 4; ++nt) {
                int n = nc * 128 + 64 * cw + 16 * nt + l15;
                if (n < NH) crow[n] = acc[mt][nt][r];
            }
        }
}

// ---------------------------------------------------------------------------
// Kernel 5: pairwise GEMM + fused FFN epilogue. Fully double-buffered,
// single barrier per iter. M=128 (2 trig x 64 e), N=320, kreal=16/iter,
// 64 iters. LDS 60 KB -> 2 blocks/CU. grid = (16 b, 16 tp, 2 nc), block 256.
__global__ __launch_bounds__(256, 2) void pair_mfma_kernel(
    const float* __restrict__ trig, const float* __restrict__ ent,
    const __bf16* __restrict__ W0pair, const float* __restrict__ b0,
    const float* __restrict__ pre_t, const float* __restrict__ pre_e,
    const float* __restrict__ W1, const float* __restrict__ b1,
    float* __restrict__ out) {
    __shared__ __bf16 Xs[2][128 * 32];   // 2 x 8 KB
    __shared__ __bf16 Bs[2][320 * 32];   // 2 x 20 KB
    __shared__ __bf16 Ts[2048];          // 4 KB: [trigger 2][k 1024] bf16
    int b = blockIdx.x, tp = blockIdx.y, nc = blockIdx.z;
    int tid = threadIdx.x;
    int lane = tid & 63, w = tid >> 6, rw = w & 1, cw = w >> 1;
    int q = lane >> 4, l15 = lane & 15;
    int xr = tid >> 1, xh = tid & 1;     // X staging: row 0..127, k-half
    const float* t0row = trig + (size_t)(b * NT + tp * 2) * ND;
    const float* erow = ent + (size_t)(b * NE + (xr & 63)) * ND;
    const __bf16* imgbase = W0pair + (size_t)nc * 64 * IMGQ;
    f32x4 acc[4][10] = {};
    float4 ef4[2];

    auto dma_b = [&](int it, int buf) {
        const __bf16* img = imgbase + (size_t)it * IMGQ + w * 2560;
        __bf16* lds = &Bs[buf][w * 2560];
#pragma unroll
        for (int i = 0; i < 5; ++i)
            dma16(img + i * 512 + lane * 8, lds + i * 512);
    };
    auto load_e = [&](int it) {
        const float* er = erow + it * 16 + xh * 8;
        ef4[0] = *(const float4*)er;
        ef4[1] = *(const float4*)(er + 4);
    };
    auto write_x = [&](int it, int buf) {
        bf16x8 tv = *(const bf16x8*)&Ts[(xr >> 6) * 1024 + it * 16 + xh * 8];
        float tf[8], ef[8];
#pragma unroll
        for (int j = 0; j < 8; ++j) tf[j] = (float)tv[j];
        ef[0] = ef4[0].x; ef[1] = ef4[0].y; ef[2] = ef4[0].z; ef[3] = ef4[0].w;
        ef[4] = ef4[1].x; ef[5] = ef4[1].y; ef[6] = ef4[1].z; ef[7] = ef4[1].w;
        int sp = (((xr >> 1) + xh) & 3) * 8;
        int sd = (((xr >> 1) + 2 + xh) & 3) * 8;
        __bf16* xb = &Xs[buf][xr * 32];
        *(bf16x8*)(xb + sp) = pack8(
            tf[0] * ef[0], tf[1] * ef[1], tf[2] * ef[2], tf[3] * ef[3],
            tf[4] * ef[4], tf[5] * ef[5], tf[6] * ef[6], tf[7] * ef[7]);
        *(bf16x8*)(xb + sd) = pack8(
            fabsf(tf[0] - ef[0]), fabsf(tf[1] - ef[1]),
            fabsf(tf[2] - ef[2]), fabsf(tf[3] - ef[3]),
            fabsf(tf[4] - ef[4]), fabsf(tf[5] - ef[5]),
            fabsf(tf[6] - ef[6]), fabsf(tf[7] - ef[7]));
    };
    auto mfma_tile = [&](int buf) {
        const __bf16* X = Xs[buf];
        const __bf16* Bb = Bs[buf];
        bf16x8 af[4];
#pragma unroll
        for (int mt = 0; mt < 4; ++mt) {
            int r = 64 * rw + 16 * mt + l15;
            af[mt] = *(const bf16x8*)&X[r * 32 + (((r >> 1) + q) & 3) * 8];
        }
#pragma unroll
        for (int nt = 0; nt < 10; ++nt) {
            int r = 160 * cw + 16 * nt + l15;
            bf16x8 bv = *(const bf16x8*)&Bb[r * 32 + (((r >> 1) + q) & 3) * 8];
#pragma unroll
            for (int mt = 0; mt < 4; ++mt)
                acc[mt][nt] = __builtin_amdgcn_mfma_f32_16x16x32_bf16(
                    af[mt], bv, acc[mt][nt], 0, 0, 0);
        }
    };

    // --- preamble: trigger rows -> Ts (bf16); first tiles in flight ---
    {
        int k0 = (tid & 127) * 8;
        const float* src = t0row + (tid >> 7) * ND + k0;
        float4 va = *(const float4*)src;
        float4 vb = *(const float4*)(src + 4);
        *(bf16x8*)&Ts[tid * 8] =
            pack8(va.x, va.y, va.z, va.w, vb.x, vb.y, vb.z, vb.w);
    }
    dma_b(0, 0);
    load_e(0);
    __syncthreads();             // Ts + B(0) ready
    write_x(0, 0);
    __syncthreads();             // X(0) visible

    for (int it = 0; it < 64; ++it) {
        int cur = it & 1, nxt = cur ^ 1;
        if (it < 63) {
            load_e(it + 1);      // global prefetch (hides under MFMA)
            dma_b(it + 1, nxt);  // async DMA into other buffer
        }
        mfma_tile(cur);
        if (it < 63) write_x(it + 1, nxt);
        __syncthreads();         // single barrier: drains DMA, publishes X
    }

    // --- epilogue: h = relu(acc + pre_t + pre_e + b0); out += h @ W1 ---
    int tglob = b * NT + tp * 2 + rw;
    const float* preT = pre_t + (size_t)tglob * NH;
    float w10[10], w11[10], b0v[10], ptv[10];
    int nbase = nc * 320 + 160 * cw + l15;
#pragma unroll
    for (int nt = 0; nt < 10; ++nt) {
        int n = nbase + 16 * nt;
        bool v = n < NH;
        w10[nt] = v ? W1[2 * n] : 0.f;
        w11[nt] = v ? W1[2 * n + 1] : 0.f;
        b0v[nt] = v ? b0[n] : 0.f;
        ptv[nt] = v ? preT[n] : 0.f;
    }
    float b10 = b1[0], b11 = b1[1];
    bool lead = (l15 == 0);
    bool addb = (nc == 0) && (cw == 0);
#pragma unroll
    for (int mt = 0; mt < 4; ++mt) {
#pragma unroll
        for (int r = 0; r < 4; ++r) {
            int e = 16 * mt + 4 * q + r;
            const float* preE = pre_e + (size_t)(b * NE + e) * NH;
            float s0 = 0.f, s1 = 0.f;
#pragma unroll
            for (int nt = 0; nt < 10; ++nt) {
                int n = nbase + 16 * nt;
                float pe = (n < NH) ? preE[n] : 0.f;
                float h = acc[mt][nt][r] + ptv[nt] + pe + b0v[nt];
                h = fmaxf(h, 0.f);
                s0 += h * w10[nt];
                s1 += h * w11[nt];
            }
#pragma unroll
            for (int m = 8; m >= 1; m >>= 1) {
                s0 += __shfl_xor(s0, m);
                s1 += __shfl_xor(s1, m);
            }
            if (lead) {
                if (addb) { s0 += b10; s1 += b11; }
                float* o = out + ((size_t)(tglob * NE + e)) * 2;
                atomicAdd(o, s0);
                atomicAdd(o + 1, s1);
            }
        }
    }
}

// ---------------------------------------------------------------------------
extern "C" void kernel_launch(void* const* d_in, const int* in_sizes, int n_in,
                              void* d_out, int out_size, void* d_ws,
                              size_t ws_size, hipStream_t stream) {
    const float* piece = (const float*)d_in[0];
    const int* widx = (const int*)d_in[1];
    const int* tidx = (const int*)d_in[2];
    const int* eidx = (const int*)d_in[3];
    const float* W0 = (const float*)d_in[4];
    const float* b0 = (const float*)d_in[5];
    const float* W1 = (const float*)d_in[6];
    const float* b1 = (const float*)d_in[7];
    float* out = (float*)d_out;

    float* ws = (float*)d_ws;
    float* word = ws;                               // NB*NW*ND f32 (dead after span_mean)
    float* trig = word + (size_t)NB * NW * ND;      // NB*NT*ND f32
    float* ent = trig + (size_t)NB * NT * ND;       // NB*NE*ND f32
    float* pre_t = ent + (size_t)NB * NE * ND;      // NB*NT*NH f32
    float* pre_e = pre_t + (size_t)NB * NT * NH;    // NB*NE*NH f32
    __bf16* W0pre = (__bf16*)word;                  // 5*32*IMGP bf16 (aliases dead word)
    __bf16* W0pair = W0pre + (size_t)5 * 32 * IMGP; // 2*64*IMGQ bf16

    hipMemsetAsync(d_out, 0, (size_t)out_size * sizeof(float), stream);

    word_mean_kernel<<<NB * NW, 256, 0, stream>>>(piece, widx, word);
    span_mean_kernel<<<NB * (NT + NE), 256, 0, stream>>>(word, tidx, eidx, trig, ent);
    // word is dead from here on; swizzle kernels overwrite it with images
    w0_swizzle_kernel<<<dim3(32, 5), 256, 0, stream>>>(W0, W0pre);
    w0_pair_kernel<<<dim3(64, 2, 4), 256, 0, stream>>>(W0, W0pair);
    pre_mfma_kernel<<<dim3(12, 5), 256, 0, stream>>>(trig, ent, W0pre, pre_t, pre_e);
    pair_mfma_kernel<<<dim3(16, 16, 2), 256, 0, stream>>>(
        trig, ent, W0pair, b0, pre_t, pre_e, W1, b1, out);
}

// Round 9
// 233.769 us; speedup vs baseline: 1.0738x; 1.0738x over previous
//
#include <hip/hip_runtime.h>
#include <cstddef>
#include <cstdint>

typedef float f32x4 __attribute__((ext_vector_type(4)));
typedef __bf16 bf16x8 __attribute__((ext_vector_type(8)));

constexpr int NB = 16;   // batch
constexpr int NP = 512;  // pieces
constexpr int ND = 1024; // dim
constexpr int NW = 400;  // words
constexpr int NT = 32;   // triggers
constexpr int NE = 64;   // entities
constexpr int NH = 600;  // hidden
// W0pre: [nc=5][kb=32] images (128n x 64k bf16, XOR swizzle) - slices a,b.
// W0pair: [z=4][it=64] images (160n x 32c bf16, rotation swizzle):
//   chunk c<2 -> W0c k = it*16 + c*8 + j ; c>=2 -> W0d k = it*16 + (c-2)*8 + j
//   elem at row r, slot ((r>>1) + c) & 3 (addr r*32 + slot*8); n = z*160 + r,
//   zero-padded for n >= 600.
constexpr int IMGP = 128 * 64;   // W0pre image elems
constexpr int IMGQ = 160 * 32;   // W0pair image elems (5120)

__device__ inline bf16x8 pack8(float a0, float a1, float a2, float a3,
                               float a4, float a5, float a6, float a7) {
    bf16x8 v;
    v[0] = (__bf16)a0; v[1] = (__bf16)a1; v[2] = (__bf16)a2; v[3] = (__bf16)a3;
    v[4] = (__bf16)a4; v[5] = (__bf16)a5; v[6] = (__bf16)a6; v[7] = (__bf16)a7;
    return v;
}

__device__ inline void dma16(const void* g, void* l) {
    __builtin_amdgcn_global_load_lds(
        (const __attribute__((address_space(1))) uint32_t*)g,
        (__attribute__((address_space(3))) uint32_t*)l, 16, 0, 0);
}

// ---------------------------------------------------------------------------
// Kernel 1: word means over piece intervals. grid = NB*NW, block = 256.
__global__ __launch_bounds__(256) void word_mean_kernel(
    const float* __restrict__ piece, const int* __restrict__ widx,
    float* __restrict__ word) {
    int bw = blockIdx.x;
    int b = bw / NW;
    int s = widx[bw * 2], e = widx[bw * 2 + 1];
    int col = threadIdx.x * 4;
    const float* base = piece + (size_t)b * NP * ND + col;
    float4 acc = make_float4(0.f, 0.f, 0.f, 0.f);
    for (int r = s; r < e; ++r) {
        float4 v = *(const float4*)(base + (size_t)r * ND);
        acc.x += v.x; acc.y += v.y; acc.z += v.z; acc.w += v.w;
    }
    float inv = 1.0f / (float)(e - s);
    acc.x *= inv; acc.y *= inv; acc.z *= inv; acc.w *= inv;
    *(float4*)(word + (size_t)bw * ND + col) = acc;
}

// ---------------------------------------------------------------------------
// Kernel 2: span means over word intervals (trig + ent in one grid).
__global__ __launch_bounds__(256) void span_mean_kernel(
    const float* __restrict__ word, const int* __restrict__ tidx,
    const int* __restrict__ eidx, float* __restrict__ trig,
    float* __restrict__ ent) {
    int id = blockIdx.x;
    const int* idx;
    float* out;
    int b;
    if (id < NB * NT) {
        b = id / NT; idx = tidx + id * 2; out = trig + (size_t)id * ND;
    } else {
        int id2 = id - NB * NT;
        b = id2 / NE; idx = eidx + id2 * 2; out = ent + (size_t)id2 * ND;
    }
    int s = idx[0], e = idx[1];
    int col = threadIdx.x * 4;
    const float* base = word + (size_t)b * NW * ND + col;
    float4 acc = make_float4(0.f, 0.f, 0.f, 0.f);
    for (int r = s; r < e; ++r) {
        float4 v = *(const float4*)(base + (size_t)r * ND);
        acc.x += v.x; acc.y += v.y; acc.z += v.z; acc.w += v.w;
    }
    float inv = 1.0f / (float)(e - s);
    acc.x *= inv; acc.y *= inv; acc.z *= inv; acc.w *= inv;
    *(float4*)(out + col) = acc;
}

// ---------------------------------------------------------------------------
// Kernel 3: both W0 image builders in one launch. grid = 160 + 256 blocks.
// Blocks [0,160): W0pre (kb = id & 31, nc = id >> 5), XOR swizzle.
// Blocks [160,416): W0pair (it = e & 63, z = e >> 6), rotation swizzle.
__global__ __launch_bounds__(256) void w0_build_kernel(
    const float* __restrict__ W0, __bf16* __restrict__ W0pre,
    __bf16* __restrict__ W0pair) {
    __shared__ float T[64][132];
    int id = blockIdx.x;
    int t = threadIdx.x;
    if (id < 160) {
        int kb = id & 31, nc = id >> 5;
        {
            int kl = t >> 2;
            int n0 = (t & 3) * 32;
            int kg = kb * 64 + kl;
            const float* src = W0 + (size_t)kg * NH + nc * 128 + n0;
#pragma unroll
            for (int g = 0; g < 8; ++g) {
                int n = nc * 128 + n0 + g * 4;
                float4 v = (n < NH) ? *(const float4*)(src + g * 4)
                                    : make_float4(0.f, 0.f, 0.f, 0.f);
                *(float4*)&T[kl][n0 + g * 4] = v;
            }
        }
        __syncthreads();
#pragma unroll
        for (int s = 0; s < 4; ++s) {
            int idx = t * 4 + s;
            int row = idx >> 3, c = idx & 7;
            bf16x8 v = pack8(T[c * 8 + 0][row], T[c * 8 + 1][row],
                             T[c * 8 + 2][row], T[c * 8 + 3][row],
                             T[c * 8 + 4][row], T[c * 8 + 5][row],
                             T[c * 8 + 6][row], T[c * 8 + 7][row]);
            __bf16* img = W0pre + ((size_t)nc * 32 + kb) * IMGP;
            *(bf16x8*)&img[row * 64 + ((c ^ (row & 7)) << 3)] = v;
        }
    } else {
        int e = id - 160;
        int it = e & 63, z = e >> 6;
        float (*Tp)[164] = reinterpret_cast<float(*)[164]>(&T[0][0]);
        {
            int k = t >> 3, seg = t & 7;   // 20 n per thread
            int korig = (k < 16) ? (2048 + it * 16 + k)
                                 : (3072 + it * 16 + (k - 16));
            const float* src = W0 + (size_t)korig * NH;
#pragma unroll
            for (int g = 0; g < 5; ++g) {
                int n = z * 160 + seg * 20 + g * 4;
                float4 v = (n < NH) ? *(const float4*)(src + n)
                                    : make_float4(0.f, 0.f, 0.f, 0.f);
                *(float4*)&Tp[k][seg * 20 + g * 4] = v;
            }
        }
        __syncthreads();
        __bf16* img = W0pair + ((size_t)z * 64 + it) * IMGQ;
#pragma unroll
        for (int s = 0; s < 3; ++s) {
            int idx = s * 256 + t;   // (r, c)
            if (idx < 640) {
                int r = idx >> 2, c = idx & 3;
                bf16x8 v = pack8(Tp[c * 8 + 0][r], Tp[c * 8 + 1][r],
                                 Tp[c * 8 + 2][r], Tp[c * 8 + 3][r],
                                 Tp[c * 8 + 4][r], Tp[c * 8 + 5][r],
                                 Tp[c * 8 + 6][r], Tp[c * 8 + 7][r]);
                int slot = ((r >> 1) + c) & 3;
                *(bf16x8*)&img[r * 32 + slot * 8] = v;
            }
        }
    }
}

// ---------------------------------------------------------------------------
// Kernel 4: pre-projection GEMMs. 64x64 tiles, block = 256 (4 waves, 2x2 of
// 32x32). grid = (24 mtile [0..7 trig, 8..23 ent], 10 ntile of 64).
__global__ __launch_bounds__(256) void pre_mfma_kernel(
    const float* __restrict__ trig, const float* __restrict__ ent,
    const __bf16* __restrict__ W0pre, float* __restrict__ pre_t,
    float* __restrict__ pre_e) {
    __shared__ __bf16 As[64 * 64];
    __shared__ __bf16 Bs[64 * 64];
    int mt8 = blockIdx.x, ntile = blockIdx.y;
    const float* A;
    float* C;
    int kbofs, mbase;
    if (mt8 < 8) { A = trig; C = pre_t; kbofs = 0;  mbase = mt8 * 64; }
    else         { A = ent;  C = pre_e; kbofs = 16; mbase = (mt8 - 8) * 64; }
    int tid = threadIdx.x;
    int lane = tid & 63, w = tid >> 6, rw = w & 1, cw = w >> 1;
    int q = lane >> 4, l15 = lane & 15, sa = l15 & 7;
    int nc = ntile >> 1, half = ntile & 1;
    const __bf16* imgbase =
        W0pre + ((size_t)nc * 32 + kbofs) * IMGP + half * 4096;
    int ar = tid >> 2, seg = tid & 3;
    f32x4 acc[2][2] = {};

    for (int it = 0; it < 16; ++it) {
        __syncthreads();
        // B: 4096 elems (8 x 512) via DMA
        const __bf16* img = imgbase + (size_t)it * IMGP;
#pragma unroll
        for (int i = 0; i < 2; ++i) {
            int idx = i * 4 + w;
            dma16(img + idx * 512 + lane * 8, (__bf16*)Bs + idx * 512);
        }
        // A: f32 -> bf16 swizzled; thread = (row ar, k-quarter seg)
        {
            const float* src = A + (size_t)(mbase + ar) * ND + it * 64;
#pragma unroll
            for (int i = 0; i < 2; ++i) {
                int c = seg * 2 + i;
                float4 a0 = *(const float4*)(src + c * 8);
                float4 a1 = *(const float4*)(src + c * 8 + 4);
                *(bf16x8*)&As[ar * 64 + ((c ^ (ar & 7)) << 3)] =
                    pack8(a0.x, a0.y, a0.z, a0.w, a1.x, a1.y, a1.z, a1.w);
            }
        }
        __syncthreads();
#pragma unroll
        for (int ks = 0; ks < 2; ++ks) {
            int coff = ((q ^ sa) ^ (ks << 2)) << 3;
            bf16x8 af[2];
#pragma unroll
            for (int mt = 0; mt < 2; ++mt)
                af[mt] = *(const bf16x8*)&As[(32 * rw + 16 * mt + l15) * 64 + coff];
#pragma unroll
            for (int nt = 0; nt < 2; ++nt) {
                bf16x8 bf = *(const bf16x8*)&Bs[(32 * cw + 16 * nt + l15) * 64 + coff];
#pragma unroll
                for (int mt = 0; mt < 2; ++mt)
                    acc[mt][nt] = __builtin_amdgcn_mfma_f32_16x16x32_bf16(
                        af[mt], bf, acc[mt][nt], 0, 0, 0);
            }
        }
    }
#pragma unroll
    for (int mt = 0; mt < 2; ++mt)
#pragma unroll
        for (int r = 0; r < 4; ++r) {
            float* crow =
                C + (size_t)(mbase + 32 * rw + 16 * mt + 4 * q + r) * NH;
#pragma unroll
            for (int nt = 0; nt < 2; ++nt) {
                int n = ntile * 64 + 32 * cw + 16 * nt + l15;
                if (n < NH) crow[n] = acc[mt][nt][r];
            }
        }
}

// ---------------------------------------------------------------------------
// Kernel 5: pairwise GEMM + fused FFN epilogue. Fully double-buffered,
// single barrier per iter. M=128 (2 trig x 64 e), N=160 per block, kreal=16,
// 64 iters. LDS 40 KB -> 4 blocks/CU. grid = (16 b, 16 tp, 4 z), block 256.
__global__ __launch_bounds__(256, 4) void pair_mfma_kernel(
    const float* __restrict__ trig, const float* __restrict__ ent,
    const __bf16* __restrict__ W0pair, const float* __restrict__ b0,
    const float* __restrict__ pre_t, const float* __restrict__ pre_e,
    const float* __restrict__ W1, const float* __restrict__ b1,
    float* __restrict__ out) {
    __shared__ __bf16 Xs[2][128 * 32];   // 2 x 8 KB
    __shared__ __bf16 Bs[2][160 * 32];   // 2 x 10 KB
    __shared__ __bf16 Ts[2048];          // 4 KB: [trigger 2][k 1024] bf16
    int b = blockIdx.x, tp = blockIdx.y, z = blockIdx.z;
    int tid = threadIdx.x;
    int lane = tid & 63, w = tid >> 6, rw = w & 1, cw = w >> 1;
    int q = lane >> 4, l15 = lane & 15;
    int xr = tid >> 1, xh = tid & 1;     // X staging: row 0..127, k-half
    const float* t0row = trig + (size_t)(b * NT + tp * 2) * ND;
    const float* erow = ent + (size_t)(b * NE + (xr & 63)) * ND;
    const __bf16* imgbase = W0pair + (size_t)z * 64 * IMGQ;
    f32x4 acc[4][5] = {};
    float4 ef4[2];

    auto dma_b = [&](int it, int buf) {
        const __bf16* img = imgbase + (size_t)it * IMGQ;
        __bf16* lds = Bs[buf];
#pragma unroll
        for (int i = 0; i < 3; ++i) {
            int idx = i * 4 + w;        // 0..11; wave-uniform skip of 10,11
            if (idx < 10)
                dma16(img + idx * 512 + lane * 8, lds + idx * 512);
        }
    };
    auto load_e = [&](int it) {
        const float* er = erow + it * 16 + xh * 8;
        ef4[0] = *(const float4*)er;
        ef4[1] = *(const float4*)(er + 4);
    };
    auto write_x = [&](int it, int buf) {
        bf16x8 tv = *(const bf16x8*)&Ts[(xr >> 6) * 1024 + it * 16 + xh * 8];
        float tf[8], ef[8];
#pragma unroll
        for (int j = 0; j < 8; ++j) tf[j] = (float)tv[j];
        ef[0] = ef4[0].x; ef[1] = ef4[0].y; ef[2] = ef4[0].z; ef[3] = ef4[0].w;
        ef[4] = ef4[1].x; ef[5] = ef4[1].y; ef[6] = ef4[1].z; ef[7] = ef4[1].w;
        int sp = (((xr >> 1) + xh) & 3) * 8;
        int sd = (((xr >> 1) + 2 + xh) & 3) * 8;
        __bf16* xb = &Xs[buf][xr * 32];
        *(bf16x8*)(xb + sp) = pack8(
            tf[0] * ef[0], tf[1] * ef[1], tf[2] * ef[2], tf[3] * ef[3],
            tf[4] * ef[4], tf[5] * ef[5], tf[6] * ef[6], tf[7] * ef[7]);
        *(bf16x8*)(xb + sd) = pack8(
            fabsf(tf[0] - ef[0]), fabsf(tf[1] - ef[1]),
            fabsf(tf[2] - ef[2]), fabsf(tf[3] - ef[3]),
            fabsf(tf[4] - ef[4]), fabsf(tf[5] - ef[5]),
            fabsf(tf[6] - ef[6]), fabsf(tf[7] - ef[7]));
    };
    auto mfma_tile = [&](int buf) {
        const __bf16* X = Xs[buf];
        const __bf16* Bb = Bs[buf];
        bf16x8 af[4];
#pragma unroll
        for (int mt = 0; mt < 4; ++mt) {
            int r = 64 * rw + 16 * mt + l15;
            af[mt] = *(const bf16x8*)&X[r * 32 + (((r >> 1) + q) & 3) * 8];
        }
#pragma unroll
        for (int nt = 0; nt < 5; ++nt) {
            int r = 80 * cw + 16 * nt + l15;
            bf16x8 bv = *(const bf16x8*)&Bb[r * 32 + (((r >> 1) + q) & 3) * 8];
#pragma unroll
            for (int mt = 0; mt < 4; ++mt)
                acc[mt][nt] = __builtin_amdgcn_mfma_f32_16x16x32_bf16(
                    af[mt], bv, acc[mt][nt], 0, 0, 0);
        }
    };

    // --- preamble: trigger rows -> Ts (bf16); first tiles in flight ---
    {
        int k0 = (tid & 127) * 8;
        const float* src = t0row + (tid >> 7) * ND + k0;
        float4 va = *(const float4*)src;
        float4 vb = *(const float4*)(src + 4);
        *(bf16x8*)&Ts[tid * 8] =
            pack8(va.x, va.y, va.z, va.w, vb.x, vb.y, vb.z, vb.w);
    }
    dma_b(0, 0);
    load_e(0);
    __syncthreads();             // Ts + B(0) ready
    write_x(0, 0);
    __syncthreads();             // X(0) visible

    for (int it = 0; it < 64; ++it) {
        int cur = it & 1, nxt = cur ^ 1;
        if (it < 63) {
            load_e(it + 1);      // global prefetch (hides under MFMA)
            dma_b(it + 1, nxt);  // async DMA into other buffer
        }
        mfma_tile(cur);
        if (it < 63) write_x(it + 1, nxt);
        __syncthreads();         // single barrier: drains DMA, publishes X
    }

    // --- epilogue: h = relu(acc + pre_t + pre_e + b0); out += h @ W1 ---
    int tglob = b * NT + tp * 2 + rw;
    const float* preT = pre_t + (size_t)tglob * NH;
    float w10[5], w11[5], b0v[5], ptv[5];
    int nbase = z * 160 + 80 * cw + l15;
#pragma unroll
    for (int nt = 0; nt < 5; ++nt) {
        int n = nbase + 16 * nt;
        bool v = n < NH;
        w10[nt] = v ? W1[2 * n] : 0.f;
        w11[nt] = v ? W1[2 * n + 1] : 0.f;
        b0v[nt] = v ? b0[n] : 0.f;
        ptv[nt] = v ? preT[n] : 0.f;
    }
    float b10 = b1[0], b11 = b1[1];
    bool lead = (l15 == 0);
    bool addb = (z == 0) && (cw == 0);
#pragma unroll
    for (int mt = 0; mt < 4; ++mt) {
#pragma unroll
        for (int r = 0; r < 4; ++r) {
            int e = 16 * mt + 4 * q + r;
            const float* preE = pre_e + (size_t)(b * NE + e) * NH;
            float s0 = 0.f, s1 = 0.f;
#pragma unroll
            for (int nt = 0; nt < 5; ++nt) {
                int n = nbase + 16 * nt;
                float pe = (n < NH) ? preE[n] : 0.f;
                float h = acc[mt][nt][r] + ptv[nt] + pe + b0v[nt];
                h = fmaxf(h, 0.f);
                s0 += h * w10[nt];
                s1 += h * w11[nt];
            }
#pragma unroll
            for (int m = 8; m >= 1; m >>= 1) {
                s0 += __shfl_xor(s0, m);
                s1 += __shfl_xor(s1, m);
            }
            if (lead) {
                if (addb) { s0 += b10; s1 += b11; }
                float* o = out + ((size_t)(tglob * NE + e)) * 2;
                atomicAdd(o, s0);
                atomicAdd(o + 1, s1);
            }
        }
    }
}

// ---------------------------------------------------------------------------
extern "C" void kernel_launch(void* const* d_in, const int* in_sizes, int n_in,
                              void* d_out, int out_size, void* d_ws,
                              size_t ws_size, hipStream_t stream) {
    const float* piece = (const float*)d_in[0];
    const int* widx = (const int*)d_in[1];
    const int* tidx = (const int*)d_in[2];
    const int* eidx = (const int*)d_in[3];
    const float* W0 = (const float*)d_in[4];
    const float* b0 = (const float*)d_in[5];
    const float* W1 = (const float*)d_in[6];
    const float* b1 = (const float*)d_in[7];
    float* out = (float*)d_out;

    float* ws = (float*)d_ws;
    float* word = ws;                               // NB*NW*ND f32 (dead after span_mean)
    float* trig = word + (size_t)NB * NW * ND;      // NB*NT*ND f32
    float* ent = trig + (size_t)NB * NT * ND;       // NB*NE*ND f32
    float* pre_t = ent + (size_t)NB * NE * ND;      // NB*NT*NH f32
    float* pre_e = pre_t + (size_t)NB * NT * NH;    // NB*NE*NH f32
    __bf16* W0pre = (__bf16*)word;                  // 5*32*IMGP bf16 (aliases dead word)
    __bf16* W0pair = W0pre + (size_t)5 * 32 * IMGP; // 4*64*IMGQ bf16

    hipMemsetAsync(d_out, 0, (size_t)out_size * sizeof(float), stream);

    word_mean_kernel<<<NB * NW, 256, 0, stream>>>(piece, widx, word);
    span_mean_kernel<<<NB * (NT + NE), 256, 0, stream>>>(word, tidx, eidx, trig, ent);
    // word is dead from here on; builder overwrites it with both image sets
    w0_build_kernel<<<416, 256, 0, stream>>>(W0, W0pre, W0pair);
    pre_mfma_kernel<<<dim3(24, 10), 256, 0, stream>>>(trig, ent, W0pre, pre_t, pre_e);
    pair_mfma_kernel<<<dim3(16, 16, 4), 256, 0, stream>>>(
        trig, ent, W0pair, b0, pre_t, pre_e, W1, b1, out);
}

// Round 10
// 221.971 us; speedup vs baseline: 1.1309x; 1.0531x over previous
//
#include <hip/hip_runtime.h>
#include <cstddef>
#include <cstdint>

typedef float f32x4 __attribute__((ext_vector_type(4)));
typedef __bf16 bf16x8 __attribute__((ext_vector_type(8)));

constexpr int NB = 16;   // batch
constexpr int NP = 512;  // pieces
constexpr int ND = 1024; // dim
constexpr int NW = 400;  // words
constexpr int NT = 32;   // triggers
constexpr int NE = 64;   // entities
constexpr int NH = 600;  // hidden
// W0pre: [nc=5][kb=32] images (128n x 64k bf16, XOR swizzle) - slices a,b.
// W0pair: [nc=2][it=64] images (320n x 32c bf16, rotation swizzle):
//   chunk c<2 -> W0c k = it*16 + c*8 + j ; c>=2 -> W0d k = it*16 + (c-2)*8 + j
//   elem at row r, slot ((r>>1) + c) & 3 (addr r*32 + slot*8); n = nc*320 + r,
//   zero-padded for n >= 600.
constexpr int IMGP = 128 * 64;   // W0pre image elems
constexpr int IMGQ = 320 * 32;   // W0pair image elems

__device__ inline bf16x8 pack8(float a0, float a1, float a2, float a3,
                               float a4, float a5, float a6, float a7) {
    bf16x8 v;
    v[0] = (__bf16)a0; v[1] = (__bf16)a1; v[2] = (__bf16)a2; v[3] = (__bf16)a3;
    v[4] = (__bf16)a4; v[5] = (__bf16)a5; v[6] = (__bf16)a6; v[7] = (__bf16)a7;
    return v;
}

__device__ inline void dma16(const void* g, void* l) {
    __builtin_amdgcn_global_load_lds(
        (const __attribute__((address_space(1))) uint32_t*)g,
        (__attribute__((address_space(3))) uint32_t*)l, 16, 0, 0);
}

// ---------------------------------------------------------------------------
// Kernel 1: span means DIRECTLY from piece (mean of word means, fused).
// grid = NB*(NT+NE), block = 256 (thread = 4-float column slice).
__global__ __launch_bounds__(256) void span_mean_kernel(
    const float* __restrict__ piece, const int* __restrict__ widx,
    const int* __restrict__ tidx, const int* __restrict__ eidx,
    float* __restrict__ trig, float* __restrict__ ent) {
    int id = blockIdx.x;
    const int* idx;
    float* outp;
    int b;
    if (id < NB * NT) {
        b = id / NT; idx = tidx + id * 2; outp = trig + (size_t)id * ND;
    } else {
        int id2 = id - NB * NT;
        b = id2 / NE; idx = eidx + id2 * 2; outp = ent + (size_t)id2 * ND;
    }
    int s = idx[0], e = idx[1];
    int col = threadIdx.x * 4;
    const int* wrow = widx + b * NW * 2;
    const float* pbase = piece + (size_t)b * NP * ND + col;
    float4 acc = make_float4(0.f, 0.f, 0.f, 0.f);
    for (int w = s; w < e; ++w) {
        int ps = wrow[2 * w], pe = wrow[2 * w + 1];
        float4 wa = make_float4(0.f, 0.f, 0.f, 0.f);
        for (int p = ps; p < pe; ++p) {
            float4 v = *(const float4*)(pbase + (size_t)p * ND);
            wa.x += v.x; wa.y += v.y; wa.z += v.z; wa.w += v.w;
        }
        float wi = 1.0f / (float)(pe - ps);
        acc.x += wa.x * wi; acc.y += wa.y * wi;
        acc.z += wa.z * wi; acc.w += wa.w * wi;
    }
    float inv = 1.0f / (float)(e - s);
    acc.x *= inv; acc.y *= inv; acc.z *= inv; acc.w *= inv;
    *(float4*)(outp + col) = acc;
}

// ---------------------------------------------------------------------------
// Kernel 2: W0 image builders + d_out zeroing, one launch. grid = 704.
// id in [0,160): W0pre (kb = id&31, nc = id>>5), XOR swizzle.
// id in [160,672): W0pair (e = id-160: it = e&63, nc = (e>>6)&1, zz = e>>7).
// id in [672,704): zero d_out (replaces hipMemsetAsync launch).
__global__ __launch_bounds__(256) void build_kernel(
    const float* __restrict__ W0, __bf16* __restrict__ W0pre,
    __bf16* __restrict__ W0pair, float* __restrict__ out, int out_size) {
    __shared__ float T[64][132];
    int id = blockIdx.x;
    int t = threadIdx.x;
    if (id < 160) {
        int kb = id & 31, nc = id >> 5;
        {
            int kl = t >> 2;
            int n0 = (t & 3) * 32;
            int kg = kb * 64 + kl;
            const float* src = W0 + (size_t)kg * NH + nc * 128 + n0;
#pragma unroll
            for (int g = 0; g < 8; ++g) {
                int n = nc * 128 + n0 + g * 4;
                float4 v = (n < NH) ? *(const float4*)(src + g * 4)
                                    : make_float4(0.f, 0.f, 0.f, 0.f);
                *(float4*)&T[kl][n0 + g * 4] = v;
            }
        }
        __syncthreads();
#pragma unroll
        for (int s = 0; s < 4; ++s) {
            int idx = t * 4 + s;
            int row = idx >> 3, c = idx & 7;
            bf16x8 v = pack8(T[c * 8 + 0][row], T[c * 8 + 1][row],
                             T[c * 8 + 2][row], T[c * 8 + 3][row],
                             T[c * 8 + 4][row], T[c * 8 + 5][row],
                             T[c * 8 + 6][row], T[c * 8 + 7][row]);
            __bf16* img = W0pre + ((size_t)nc * 32 + kb) * IMGP;
            *(bf16x8*)&img[row * 64 + ((c ^ (row & 7)) << 3)] = v;
        }
    } else if (id < 672) {
        int e = id - 160;
        int it = e & 63, nc = (e >> 6) & 1, zz = e >> 7;
        float (*Tp)[84] = reinterpret_cast<float(*)[84]>(&T[0][0]);
        {
            int kidx = t >> 3, part = t & 7;   // 10 n per thread
            int korig = (kidx < 16) ? (2048 + it * 16 + kidx)
                                    : (3072 + it * 16 + (kidx - 16));
            const float* src = W0 + (size_t)korig * NH;
#pragma unroll
            for (int g = 0; g < 10; ++g) {
                int n = nc * 320 + zz * 80 + part * 10 + g;
                Tp[kidx][part * 10 + g] = (n < NH) ? src[n] : 0.0f;
            }
        }
        __syncthreads();
        __bf16* img = W0pair + ((size_t)nc * 64 + it) * IMGQ;
#pragma unroll
        for (int s = 0; s < 2; ++s) {
            int idx = s * 256 + t;   // (rloc, c)
            if (idx < 320) {
                int rloc = idx >> 2, c = idx & 3;
                bf16x8 v = pack8(Tp[c * 8 + 0][rloc], Tp[c * 8 + 1][rloc],
                                 Tp[c * 8 + 2][rloc], Tp[c * 8 + 3][rloc],
                                 Tp[c * 8 + 4][rloc], Tp[c * 8 + 5][rloc],
                                 Tp[c * 8 + 6][rloc], Tp[c * 8 + 7][rloc]);
                int rg = zz * 80 + rloc;
                int slot = ((rg >> 1) + c) & 3;
                *(bf16x8*)&img[rg * 32 + slot * 8] = v;
            }
        }
    } else {
        int j = ((id - 672) * 256 + t) * 8;
        float4 z = make_float4(0.f, 0.f, 0.f, 0.f);
        if (j + 8 <= out_size) {
            *(float4*)(out + j) = z;
            *(float4*)(out + j + 4) = z;
        }
    }
}

// ---------------------------------------------------------------------------
// Kernel 3: pre-projection GEMMs. 64x64 tiles, block = 256 (4 waves, 2x2 of
// 32x32). grid = (24 mtile [0..7 trig, 8..23 ent], 10 ntile of 64).
__global__ __launch_bounds__(256) void pre_mfma_kernel(
    const float* __restrict__ trig, const float* __restrict__ ent,
    const __bf16* __restrict__ W0pre, float* __restrict__ pre_t,
    float* __restrict__ pre_e) {
    __shared__ __bf16 As[64 * 64];
    __shared__ __bf16 Bs[64 * 64];
    int mt8 = blockIdx.x, ntile = blockIdx.y;
    const float* A;
    float* C;
    int kbofs, mbase;
    if (mt8 < 8) { A = trig; C = pre_t; kbofs = 0;  mbase = mt8 * 64; }
    else         { A = ent;  C = pre_e; kbofs = 16; mbase = (mt8 - 8) * 64; }
    int tid = threadIdx.x;
    int lane = tid & 63, w = tid >> 6, rw = w & 1, cw = w >> 1;
    int q = lane >> 4, l15 = lane & 15, sa = l15 & 7;
    int nc = ntile >> 1, half = ntile & 1;
    const __bf16* imgbase =
        W0pre + ((size_t)nc * 32 + kbofs) * IMGP + half * 4096;
    int ar = tid >> 2, seg = tid & 3;
    f32x4 acc[2][2] = {};

    for (int it = 0; it < 16; ++it) {
        __syncthreads();
        const __bf16* img = imgbase + (size_t)it * IMGP;
#pragma unroll
        for (int i = 0; i < 2; ++i) {
            int idx = i * 4 + w;
            dma16(img + idx * 512 + lane * 8, (__bf16*)Bs + idx * 512);
        }
        {
            const float* src = A + (size_t)(mbase + ar) * ND + it * 64;
#pragma unroll
            for (int i = 0; i < 2; ++i) {
                int c = seg * 2 + i;
                float4 a0 = *(const float4*)(src + c * 8);
                float4 a1 = *(const float4*)(src + c * 8 + 4);
                *(bf16x8*)&As[ar * 64 + ((c ^ (ar & 7)) << 3)] =
                    pack8(a0.x, a0.y, a0.z, a0.w, a1.x, a1.y, a1.z, a1.w);
            }
        }
        __syncthreads();
#pragma unroll
        for (int ks = 0; ks < 2; ++ks) {
            int coff = ((q ^ sa) ^ (ks << 2)) << 3;
            bf16x8 af[2];
#pragma unroll
            for (int mt = 0; mt < 2; ++mt)
                af[mt] = *(const bf16x8*)&As[(32 * rw + 16 * mt + l15) * 64 + coff];
#pragma unroll
            for (int nt = 0; nt < 2; ++nt) {
                bf16x8 bf = *(const bf16x8*)&Bs[(32 * cw + 16 * nt + l15) * 64 + coff];
#pragma unroll
                for (int mt = 0; mt < 2; ++mt)
                    acc[mt][nt] = __builtin_amdgcn_mfma_f32_16x16x32_bf16(
                        af[mt], bf, acc[mt][nt], 0, 0, 0);
            }
        }
    }
#pragma unroll
    for (int mt = 0; mt < 2; ++mt)
#pragma unroll
        for (int r = 0; r < 4; ++r) {
            float* crow =
                C + (size_t)(mbase + 32 * rw + 16 * mt + 4 * q + r) * NH;
#pragma unroll
            for (int nt = 0; nt < 2; ++nt) {
                int n = ntile * 64 + 32 * cw + 16 * nt + l15;
                if (n < NH) crow[n] = acc[mt][nt][r];
            }
        }
}

// ---------------------------------------------------------------------------
// Kernel 4: pairwise GEMM + fused FFN epilogue (round-8 best config).
// Fully double-buffered, single barrier per iter. M=128 (2 trig x 64 e),
// N=320, kreal=16, 64 iters. LDS 60 KB -> 2 blocks/CU.
// grid = (16 b, 16 tp, 2 nc), block 256.
__global__ __launch_bounds__(256, 2) void pair_mfma_kernel(
    const float* __restrict__ trig, const float* __restrict__ ent,
    const __bf16* __restrict__ W0pair, const float* __restrict__ b0,
    const float* __restrict__ pre_t, const float* __restrict__ pre_e,
    const float* __restrict__ W1, const float* __restrict__ b1,
    float* __restrict__ out) {
    __shared__ __bf16 Xs[2][128 * 32];   // 2 x 8 KB
    __shared__ __bf16 Bs[2][320 * 32];   // 2 x 20 KB
    __shared__ __bf16 Ts[2048];          // 4 KB: [trigger 2][k 1024] bf16
    int b = blockIdx.x, tp = blockIdx.y, nc = blockIdx.z;
    int tid = threadIdx.x;
    int lane = tid & 63, w = tid >> 6, rw = w & 1, cw = w >> 1;
    int q = lane >> 4, l15 = lane & 15;
    int xr = tid >> 1, xh = tid & 1;     // X staging: row 0..127, k-half
    const float* t0row = trig + (size_t)(b * NT + tp * 2) * ND;
    const float* erow = ent + (size_t)(b * NE + (xr & 63)) * ND;
    const __bf16* imgbase = W0pair + (size_t)nc * 64 * IMGQ;
    f32x4 acc[4][10] = {};
    float4 ef4[2];

    auto dma_b = [&](int it, int buf) {
        const __bf16* img = imgbase + (size_t)it * IMGQ + w * 2560;
        __bf16* lds = &Bs[buf][w * 2560];
#pragma unroll
        for (int i = 0; i < 5; ++i)
            dma16(img + i * 512 + lane * 8, lds + i * 512);
    };
    auto load_e = [&](int it) {
        const float* er = erow + it * 16 + xh * 8;
        ef4[0] = *(const float4*)er;
        ef4[1] = *(const float4*)(er + 4);
    };
    auto write_x = [&](int it, int buf) {
        bf16x8 tv = *(const bf16x8*)&Ts[(xr >> 6) * 1024 + it * 16 + xh * 8];
        float tf[8], ef[8];
#pragma unroll
        for (int j = 0; j < 8; ++j) tf[j] = (float)tv[j];
        ef[0] = ef4[0].x; ef[1] = ef4[0].y; ef[2] = ef4[0].z; ef[3] = ef4[0].w;
        ef[4] = ef4[1].x; ef[5] = ef4[1].y; ef[6] = ef4[1].z; ef[7] = ef4[1].w;
        int sp = (((xr >> 1) + xh) & 3) * 8;
        int sd = (((xr >> 1) + 2 + xh) & 3) * 8;
        __bf16* xb = &Xs[buf][xr * 32];
        *(bf16x8*)(xb + sp) = pack8(
            tf[0] * ef[0], tf[1] * ef[1], tf[2] * ef[2], tf[3] * ef[3],
            tf[4] * ef[4], tf[5] * ef[5], tf[6] * ef[6], tf[7] * ef[7]);
        *(bf16x8*)(xb + sd) = pack8(
            fabsf(tf[0] - ef[0]), fabsf(tf[1] - ef[1]),
            fabsf(tf[2] - ef[2]), fabsf(tf[3] - ef[3]),
            fabsf(tf[4] - ef[4]), fabsf(tf[5] - ef[5]),
            fabsf(tf[6] - ef[6]), fabsf(tf[7] - ef[7]));
    };
    auto mfma_tile = [&](int buf) {
        const __bf16* X = Xs[buf];
        const __bf16* Bb = Bs[buf];
        bf16x8 af[4];
#pragma unroll
        for (int mt = 0; mt < 4; ++mt) {
            int r = 64 * rw + 16 * mt + l15;
            af[mt] = *(const bf16x8*)&X[r * 32 + (((r >> 1) + q) & 3) * 8];
        }
#pragma unroll
        for (int nt = 0; nt < 10; ++nt) {
            int r = 160 * cw + 16 * nt + l15;
            bf16x8 bv = *(const bf16x8*)&Bb[r * 32 + (((r >> 1) + q) & 3) * 8];
#pragma unroll
            for (int mt = 0; mt < 4; ++mt)
                acc[mt][nt] = __builtin_amdgcn_mfma_f32_16x16x32_bf16(
                    af[mt], bv, acc[mt][nt], 0, 0, 0);
        }
    };

    // --- preamble: trigger rows -> Ts (bf16); first tiles in flight ---
    {
        int k0 = (tid & 127) * 8;
        const float* src = t0row + (tid >> 7) * ND + k0;
        float4 va = *(const float4*)src;
        float4 vb = *(const float4*)(src + 4);
        *(bf16x8*)&Ts[tid * 8] =
            pack8(va.x, va.y, va.z, va.w, vb.x, vb.y, vb.z, vb.w);
    }
    dma_b(0, 0);
    load_e(0);
    __syncthreads();             // Ts + B(0) ready
    write_x(0, 0);
    __syncthreads();             // X(0) visible

    for (int it = 0; it < 64; ++it) {
        int cur = it & 1, nxt = cur ^ 1;
        if (it < 63) {
            load_e(it + 1);      // global prefetch (hides under MFMA)
            dma_b(it + 1, nxt);  // async DMA into other buffer
        }
        mfma_tile(cur);
        if (it < 63) write_x(it + 1, nxt);
        __syncthreads();         // single barrier: drains DMA, publishes X
    }

    // --- epilogue: h = relu(acc + pre_t + pre_e + b0); out += h @ W1 ---
    int tglob = b * NT + tp * 2 + rw;
    const float* preT = pre_t + (size_t)tglob * NH;
    float w10[10], w11[10], b0v[10], ptv[10];
    int nbase = nc * 320 + 160 * cw + l15;
#pragma unroll
    for (int nt = 0; nt < 10; ++nt) {
        int n = nbase + 16 * nt;
        bool v = n < NH;
        w10[nt] = v ? W1[2 * n] : 0.f;
        w11[nt] = v ? W1[2 * n + 1] : 0.f;
        b0v[nt] = v ? b0[n] : 0.f;
        ptv[nt] = v ? preT[n] : 0.f;
    }
    float b10 = b1[0], b11 = b1[1];
    bool lead = (l15 == 0);
    bool addb = (nc == 0) && (cw == 0);
#pragma unroll
    for (int mt = 0; mt < 4; ++mt) {
#pragma unroll
        for (int r = 0; r < 4; ++r) {
            int e = 16 * mt + 4 * q + r;
            const float* preE = pre_e + (size_t)(b * NE + e) * NH;
            float s0 = 0.f, s1 = 0.f;
#pragma unroll
            for (int nt = 0; nt < 10; ++nt) {
                int n = nbase + 16 * nt;
                float pe = (n < NH) ? preE[n] : 0.f;
                float h = acc[mt][nt][r] + ptv[nt] + pe + b0v[nt];
                h = fmaxf(h, 0.f);
                s0 += h * w10[nt];
                s1 += h * w11[nt];
            }
#pragma unroll
            for (int m = 8; m >= 1; m >>= 1) {
                s0 += __shfl_xor(s0, m);
                s1 += __shfl_xor(s1, m);
            }
            if (lead) {
                if (addb) { s0 += b10; s1 += b11; }
                float* o = out + ((size_t)(tglob * NE + e)) * 2;
                atomicAdd(o, s0);
                atomicAdd(o + 1, s1);
            }
        }
    }
}

// ---------------------------------------------------------------------------
extern "C" void kernel_launch(void* const* d_in, const int* in_sizes, int n_in,
                              void* d_out, int out_size, void* d_ws,
                              size_t ws_size, hipStream_t stream) {
    const float* piece = (const float*)d_in[0];
    const int* widx = (const int*)d_in[1];
    const int* tidx = (const int*)d_in[2];
    const int* eidx = (const int*)d_in[3];
    const float* W0 = (const float*)d_in[4];
    const float* b0 = (const float*)d_in[5];
    const float* W1 = (const float*)d_in[6];
    const float* b1 = (const float*)d_in[7];
    float* out = (float*)d_out;

    float* ws = (float*)d_ws;
    float* trig = ws;                               // NB*NT*ND f32
    float* ent = trig + (size_t)NB * NT * ND;       // NB*NE*ND f32
    float* pre_t = ent + (size_t)NB * NE * ND;      // NB*NT*NH f32
    float* pre_e = pre_t + (size_t)NB * NT * NH;    // NB*NE*NH f32
    __bf16* W0pre = (__bf16*)(pre_e + (size_t)NB * NE * NH); // 5*32*IMGP bf16
    __bf16* W0pair = W0pre + (size_t)5 * 32 * IMGP;          // 2*64*IMGQ bf16

    // 4 launches total (memset folded into build_kernel; word+span fused).
    build_kernel<<<704, 256, 0, stream>>>(W0, W0pre, W0pair, out, out_size);
    span_mean_kernel<<<NB * (NT + NE), 256, 0, stream>>>(
        piece, widx, tidx, eidx, trig, ent);
    pre_mfma_kernel<<<dim3(24, 10), 256, 0, stream>>>(trig, ent, W0pre,
                                                      pre_t, pre_e);
    pair_mfma_kernel<<<dim3(16, 16, 2), 256, 0, stream>>>(
        trig, ent, W0pair, b0, pre_t, pre_e, W1, b1, out);
}